// Round 14
// baseline (95.675 us; speedup 1.0000x reference)
//
#include <hip/hip_runtime.h>

static constexpr int N_NODES = 100000;
static constexpr int N_EDGES = 10000;
static constexpr int NNZ     = 1600000;

static constexpr int G1    = 256;          // K1 blocks
static constexpr int CHUNK = NNZ / G1;     // 6250
static constexpr int NRN   = 250;          // node ranges (= GF)
static constexpr int RN    = 400;          // nodes per range
static constexpr int RE    = 40;           // edges per K2 block (250*40 = 10000)
static constexpr int SLOT  = 64;           // binN entries per (range, block) slot
static constexpr int BLK   = 1024;
static constexpr int NW    = 16;           // waves per block
static constexpr int GF    = 250;          // K2 grid
static constexpr int ITER  = G1 * SLOT / BLK;  // 16 binN entries per thread

// ---------------- ws layout (bytes) ----------------
// binN @ 0          : NRN*G1*SLOT u32 = 16,384,000
// cntN @ 16,384,000 : NRN*G1 u32      = 256,000
// P_S1 @ 16,640,000 : G1*N_EDGES f    = 10,240,000
// P_B1 @ 26,880,000 : G1*N_EDGES/2 u32=  5,120,000
// v1   @ 32,000,000 : 40,000 ; v2 @ 32,040,000 : 40,000
// P_S  @ 32,080,000 : GF*N_EDGES f    = 10,000,000
// bar  @ 42,080,000 : 896 u32 (counters 3*8*32 + flags 3*32; reset by K1)

__device__ __forceinline__ void st_a(float* p, float v) {
    __hip_atomic_store(p, v, __ATOMIC_RELAXED, __HIP_MEMORY_SCOPE_AGENT);
}

__device__ __forceinline__ void bar_arrive(unsigned* bar, int phase) {
    __syncthreads();   // drains vmcnt: all prior sc1 stores are at L3
    if (threadIdx.x == 0)
        __hip_atomic_fetch_add(bar + phase * 256 + (blockIdx.x & 7) * 32, 1u,
                               __ATOMIC_RELAXED, __HIP_MEMORY_SCOPE_AGENT);
}
__device__ __forceinline__ void bar_wait(unsigned* bar, int phase) {
    if (threadIdx.x == 0) {
        unsigned* flag = bar + 768 + phase * 32;
        if (blockIdx.x == 0) {
            unsigned* cnt = bar + phase * 256;
            unsigned sum;
            do {
                __builtin_amdgcn_s_sleep(2);
                sum = 0u;
                #pragma unroll
                for (int g = 0; g < 8; ++g)
                    sum += __hip_atomic_load(cnt + g * 32, __ATOMIC_RELAXED,
                                             __HIP_MEMORY_SCOPE_AGENT);
            } while (sum < (unsigned)GF);
            __hip_atomic_store(flag, 1u, __ATOMIC_RELAXED, __HIP_MEMORY_SCOPE_AGENT);
        } else {
            while (__hip_atomic_load(flag, __ATOMIC_RELAXED,
                                     __HIP_MEMORY_SCOPE_AGENT) == 0u)
                __builtin_amdgcn_s_sleep(2);
        }
    }
    __syncthreads();
}

// K1: binN scatter + full-edge LDS aggregation of x + bar reset.
__global__ __launch_bounds__(BLK) void k_bin_agg(
        const int* __restrict__ nidx, const int* __restrict__ eidx,
        const float* __restrict__ x,
        unsigned* __restrict__ binN, unsigned* __restrict__ cntN,
        float* __restrict__ P_S1, unsigned* __restrict__ P_B1,
        unsigned* __restrict__ bar) {
    __shared__ float    sS[N_EDGES];      // 40 KB
    __shared__ unsigned sC[N_EDGES / 2];  // 20 KB (u16 pairs; <=6250/block, safe)
    __shared__ unsigned cN[NRN];          // 1 KB
    if (blockIdx.x == 0 && threadIdx.x < 896) bar[threadIdx.x] = 0u;
    for (int j = threadIdx.x; j < N_EDGES; j += BLK) sS[j] = 0.0f;
    for (int j = threadIdx.x; j < N_EDGES / 2; j += BLK) sC[j] = 0u;
    for (int j = threadIdx.x; j < NRN; j += BLK) cN[j] = 0u;
    __syncthreads();
    const int b = blockIdx.x;
    const int i0 = b * CHUNK, i1 = i0 + CHUNK;
    for (int i = i0 + threadIdx.x; i < i1; i += BLK) {
        int n = nidx[i], e = eidx[i];
        atomicAdd(&sS[e], x[n]);
        atomicAdd(&sC[e >> 1], 1u << ((e & 1) * 16));
        int rn = n / RN;
        unsigned pn = atomicAdd(&cN[rn], 1u);
        binN[((size_t)rn * G1 + b) * SLOT + pn] = ((unsigned)(n - rn * RN) << 14) | (unsigned)e;
    }
    __syncthreads();
    for (int j = threadIdx.x; j < NRN; j += BLK) cntN[(size_t)j * G1 + b] = cN[j];
    float*    ps = P_S1 + (size_t)b * N_EDGES;
    unsigned* pb = P_B1 + (size_t)b * (N_EDGES / 2);
    for (int j = threadIdx.x; j < N_EDGES; j += BLK) ps[j] = sS[j];
    for (int j = threadIdx.x; j < N_EDGES / 2; j += BLK) pb[j] = sC[j];
}

// K2: A'(reduce->v1) |bar0(prefetch binN+counts)| B(v1-acc+MLP+push) |bar1(zero eS)|
//     C(reduce->v2) |bar2(zero sS_n)| D(replay+out)
__global__ __launch_bounds__(BLK) void k_fused(
        const unsigned* __restrict__ binN, const unsigned* __restrict__ cntN,
        const float* __restrict__ P_S1, const unsigned* __restrict__ P_B1,
        const float* __restrict__ W1, const float* __restrict__ b1,
        const float* __restrict__ W2, const float* __restrict__ b2,
        float* __restrict__ v1, float* __restrict__ v2, float* __restrict__ P_S,
        unsigned* __restrict__ bar, float* __restrict__ out) {
    __shared__ float    sBig[N_EDGES];    // 40 KB
    __shared__ float    eS[NW][RE];
    __shared__ unsigned eC[NW][RE];
    __shared__ float    sS_n[RN];
    __shared__ unsigned sC_n[RN];
    __shared__ unsigned scntN[G1];
    __shared__ float    wgt[384];
    __shared__ float    y_loc[RN];

    const int b = blockIdx.x;
    const int t = threadIdx.x;
    const int wv = t >> 6;
    float my_binv = 0.0f;   // valid t < RE
    float my_dinv = 0.0f;   // valid t < RN

    // ---- Phase A': reduce K1 edge partials -> v1 (coalesced, all lanes) ----
    for (int j = t; j < NW * RE; j += BLK) { (&eS[0][0])[j] = 0.0f; (&eC[0][0])[j] = 0u; }
    __syncthreads();
    {
        const float* pv = P_S1 + (size_t)b * RE;
        for (int j = t; j < G1 * RE; j += BLK) {            // [256][40] flattened
            int g = j / RE;
            int e = j - g * RE;
            atomicAdd(&eS[wv][e], pv[(size_t)g * N_EDGES + e]);
        }
        const unsigned* pc = P_B1 + (size_t)b * (RE / 2);
        for (int j = t; j < G1 * (RE / 2); j += BLK) {      // [256][20] flattened
            int g = j / (RE / 2);
            int k = j - g * (RE / 2);
            unsigned c2 = pc[(size_t)g * (N_EDGES / 2) + k];
            atomicAdd(&eC[wv][2 * k],     c2 & 0xFFFFu);
            atomicAdd(&eC[wv][2 * k + 1], c2 >> 16);
        }
    }
    __syncthreads();
    if (t < RE) {
        float s = 0.0f; unsigned c = 0u;
        #pragma unroll
        for (int k = 0; k < NW; ++k) { s += eS[k][t]; c += eC[k][t]; }
        my_binv = (c > 0u) ? (1.0f / (float)c) : 0.0f;
        st_a(&v1[b * RE + t], s * my_binv);
    }
    bar_arrive(bar, 0);

    // ---- bar0 overlap window: binN prefetch + count accumulation + dinv ----
    if (t < RN) { sS_n[t] = 0.0f; sC_n[t] = 0u; }
    if (t < G1) scntN[t] = cntN[(size_t)b * G1 + t];
    if (t < 128) { wgt[t] = W1[t]; wgt[128 + t] = b1[t]; wgt[256 + t] = W2[t]; }
    __syncthreads();
    const unsigned* baseN = binN + (size_t)b * G1 * SLOT;
    unsigned w_reg[ITER];
    #pragma unroll
    for (int it = 0; it < ITER; ++it) {
        const int j = t + it * BLK;
        const int s = j & (SLOT - 1), bb = j >> 6;
        unsigned w = 0xFFFFFFFFu;
        if ((unsigned)s < scntN[bb]) {
            w = baseN[j];
            atomicAdd(&sC_n[w >> 14], 1u);
        }
        w_reg[it] = w;
    }
    __syncthreads();
    if (t < RN) {
        unsigned c = sC_n[t];
        my_dinv = (c > 0u) ? (1.0f / (float)c) : 0.0f;
    }
    bar_wait(bar, 0);

    // ---- Phase B: value accumulation + MLP + push ----
    for (int j = t; j < N_EDGES; j += BLK) sBig[j] = v1[j];   // plain cached loads
    __syncthreads();
    #pragma unroll
    for (int it = 0; it < ITER; ++it) {
        unsigned w = w_reg[it];
        if (w != 0xFFFFFFFFu) atomicAdd(&sS_n[w >> 14], sBig[w & 0x3FFFu]);
    }
    __syncthreads();
    if (t < RN) {
        float tt = sS_n[t] * my_dinv;
        float acc = 0.0f;
        #pragma unroll
        for (int f = 0; f < 128; ++f) {
            float h = fmaf(tt, wgt[f], wgt[128 + f]);
            h = fmaxf(h, 0.0f);
            acc = fmaf(h, wgt[256 + f], acc);
        }
        y_loc[t] = acc;
    }
    __syncthreads();
    for (int j = t; j < N_EDGES; j += BLK) sBig[j] = 0.0f;    // becomes push accum
    __syncthreads();
    #pragma unroll
    for (int it = 0; it < ITER; ++it) {
        unsigned w = w_reg[it];
        if (w != 0xFFFFFFFFu) atomicAdd(&sBig[w & 0x3FFFu], y_loc[w >> 14]);
    }
    __syncthreads();
    {
        float* ps = P_S + (size_t)b * N_EDGES;
        for (int j = t; j < N_EDGES; j += BLK) st_a(&ps[j], sBig[j]);
    }
    bar_arrive(bar, 1);
    // bar1 overlap: zero eS for phase C
    for (int j = t; j < NW * RE; j += BLK) (&eS[0][0])[j] = 0.0f;
    bar_wait(bar, 1);

    // ---- Phase C: reduce K2 edge partials -> v2 (coalesced, all lanes) ----
    {
        const float* pv = P_S + (size_t)b * RE;
        for (int j = t; j < GF * RE; j += BLK) {              // [250][40] flattened
            int g = j / RE;
            int e = j - g * RE;
            atomicAdd(&eS[wv][e], pv[(size_t)g * N_EDGES + e]);
        }
    }
    __syncthreads();
    if (t < RE) {
        float s = 0.0f;
        #pragma unroll
        for (int k = 0; k < NW; ++k) s += eS[k][t];
        st_a(&v2[b * RE + t], s * my_binv);
    }
    bar_arrive(bar, 2);
    if (t < RN) sS_n[t] = 0.0f;   // bar2 overlap: prep D
    bar_wait(bar, 2);

    // ---- Phase D: node pass 2 (register replay) + bias -> out ----
    for (int j = t; j < N_EDGES; j += BLK) sBig[j] = v2[j];   // plain cached loads
    __syncthreads();
    #pragma unroll
    for (int it = 0; it < ITER; ++it) {
        unsigned w = w_reg[it];
        if (w != 0xFFFFFFFFu) atomicAdd(&sS_n[w >> 14], sBig[w & 0x3FFFu]);
    }
    __syncthreads();
    if (t < RN) out[b * RN + t] = fmaf(sS_n[t], my_dinv, b2[0]);
}

extern "C" void kernel_launch(void* const* d_in, const int* in_sizes, int n_in,
                              void* d_out, int out_size, void* d_ws, size_t ws_size,
                              hipStream_t stream) {
    const float* x    = (const float*)d_in[0];
    const float* W1   = (const float*)d_in[1];
    const float* b1   = (const float*)d_in[2];
    const float* W2   = (const float*)d_in[3];
    const float* b2   = (const float*)d_in[4];
    const int*   nidx = (const int*)d_in[5];
    const int*   eidx = (const int*)d_in[6];
    float*       out  = (float*)d_out;

    char* ws = (char*)d_ws;
    unsigned* binN = (unsigned*)(ws + 0);
    unsigned* cntN = (unsigned*)(ws + 16384000);
    float*    P_S1 = (float*)(ws + 16640000);
    unsigned* P_B1 = (unsigned*)(ws + 26880000);
    float*    v1   = (float*)(ws + 32000000);
    float*    v2   = (float*)(ws + 32040000);
    float*    P_S  = (float*)(ws + 32080000);
    unsigned* bar  = (unsigned*)(ws + 42080000);

    k_bin_agg<<<G1, BLK, 0, stream>>>(nidx, eidx, x, binN, cntN, P_S1, P_B1, bar);
    k_fused  <<<GF, BLK, 0, stream>>>(binN, cntN, P_S1, P_B1, W1, b1, W2, b2,
                                      v1, v2, P_S, bar, out);
}

// Round 16
// 75.220 us; speedup vs baseline: 1.2719x; 1.2719x over previous
//
#include <hip/hip_runtime.h>

static constexpr int N_NODES = 100000;
static constexpr int N_EDGES = 10000;
static constexpr int NNZ     = 1600000;

static constexpr int G1    = 256;          // K1 blocks
static constexpr int CHUNK = NNZ / G1;     // 6250
static constexpr int NRN   = 250;          // node ranges (= GF)
static constexpr int RN    = 400;          // nodes per range
static constexpr int RE    = 40;           // edges per K2 block (250*40 = 10000)
static constexpr int SLOT  = 64;           // binN entries per (range, block) slot
static constexpr int BLK   = 1024;
static constexpr int NW    = 16;           // waves per block
static constexpr int GF    = 250;          // K2 grid
static constexpr int ITER  = G1 * SLOT / BLK;  // 16 binN entries per thread

// ---------------- ws layout (bytes) ----------------
// binN @ 0          : NRN*G1*SLOT u32 = 16,384,000
// cntN @ 16,384,000 : NRN*G1 u32      = 256,000
// P_S1 @ 16,640,000 : G1*N_EDGES f    = 10,240,000
// P_B1 @ 26,880,000 : G1*N_EDGES/2 u32=  5,120,000
// v1   @ 32,000,000 : 40,000 ; v2 @ 32,040,000 : 40,000
// P_S  @ 32,080,000 : GF*N_EDGES f    = 10,000,000
// bar  @ 42,080,000 : 896 u32 (counters 3*8*32 + flags 3*32; reset by K1)

__device__ __forceinline__ void st_a(float* p, float v) {
    __hip_atomic_store(p, v, __ATOMIC_RELAXED, __HIP_MEMORY_SCOPE_AGENT);
}

// Master-polling barrier (proven in R13): arrive = distributed fetch_add over 8
// padded lines; block 0's thread 0 POLLS the sum in a loop (eventual visibility
// guaranteed) and sets a single release flag; everyone else polls the flag.
// __syncthreads before the add drains vmcnt, so prior sc1 stores are at L3.
__device__ __forceinline__ void bar_arrive(unsigned* bar, int phase) {
    __syncthreads();
    if (threadIdx.x == 0)
        __hip_atomic_fetch_add(bar + phase * 256 + (blockIdx.x & 7) * 32, 1u,
                               __ATOMIC_RELAXED, __HIP_MEMORY_SCOPE_AGENT);
}
__device__ __forceinline__ void bar_wait(unsigned* bar, int phase) {
    if (threadIdx.x == 0) {
        unsigned* flag = bar + 768 + phase * 32;
        if (blockIdx.x == 0) {
            unsigned* cnt = bar + phase * 256;
            unsigned sum;
            do {
                __builtin_amdgcn_s_sleep(2);
                sum = 0u;
                #pragma unroll
                for (int g = 0; g < 8; ++g)
                    sum += __hip_atomic_load(cnt + g * 32, __ATOMIC_RELAXED,
                                             __HIP_MEMORY_SCOPE_AGENT);
            } while (sum < (unsigned)GF);
            __hip_atomic_store(flag, 1u, __ATOMIC_RELAXED, __HIP_MEMORY_SCOPE_AGENT);
        } else {
            while (__hip_atomic_load(flag, __ATOMIC_RELAXED,
                                     __HIP_MEMORY_SCOPE_AGENT) == 0u)
                __builtin_amdgcn_s_sleep(2);
        }
    }
    __syncthreads();
}

// K1: binN scatter + full-edge LDS aggregation of x + bar reset.
__global__ __launch_bounds__(BLK) void k_bin_agg(
        const int* __restrict__ nidx, const int* __restrict__ eidx,
        const float* __restrict__ x,
        unsigned* __restrict__ binN, unsigned* __restrict__ cntN,
        float* __restrict__ P_S1, unsigned* __restrict__ P_B1,
        unsigned* __restrict__ bar) {
    __shared__ float    sS[N_EDGES];      // 40 KB
    __shared__ unsigned sC[N_EDGES / 2];  // 20 KB (u16 pairs; <=6250/block, safe)
    __shared__ unsigned cN[NRN];          // 1 KB
    if (blockIdx.x == 0 && threadIdx.x < 896) bar[threadIdx.x] = 0u;
    for (int j = threadIdx.x; j < N_EDGES; j += BLK) sS[j] = 0.0f;
    for (int j = threadIdx.x; j < N_EDGES / 2; j += BLK) sC[j] = 0u;
    for (int j = threadIdx.x; j < NRN; j += BLK) cN[j] = 0u;
    __syncthreads();
    const int b = blockIdx.x;
    const int i0 = b * CHUNK, i1 = i0 + CHUNK;
    for (int i = i0 + threadIdx.x; i < i1; i += BLK) {
        int n = nidx[i], e = eidx[i];
        atomicAdd(&sS[e], x[n]);
        atomicAdd(&sC[e >> 1], 1u << ((e & 1) * 16));
        int rn = n / RN;
        unsigned pn = atomicAdd(&cN[rn], 1u);
        binN[((size_t)rn * G1 + b) * SLOT + pn] = ((unsigned)(n - rn * RN) << 14) | (unsigned)e;
    }
    __syncthreads();
    for (int j = threadIdx.x; j < NRN; j += BLK) cntN[(size_t)j * G1 + b] = cN[j];
    float*    ps = P_S1 + (size_t)b * N_EDGES;
    unsigned* pb = P_B1 + (size_t)b * (N_EDGES / 2);
    for (int j = threadIdx.x; j < N_EDGES; j += BLK) ps[j] = sS[j];
    for (int j = threadIdx.x; j < N_EDGES / 2; j += BLK) pb[j] = sC[j];
}

// K2: A'(reduce->v1) |bar0| B(node1+MLP+push) |bar1| C(reduce->v2) |bar2| D(replay+out)
__global__ __launch_bounds__(BLK) void k_fused(
        const unsigned* __restrict__ binN, const unsigned* __restrict__ cntN,
        const float* __restrict__ P_S1, const unsigned* __restrict__ P_B1,
        const float* __restrict__ W1, const float* __restrict__ b1,
        const float* __restrict__ W2, const float* __restrict__ b2,
        float* __restrict__ v1, float* __restrict__ v2, float* __restrict__ P_S,
        unsigned* __restrict__ bar, float* __restrict__ out) {
    __shared__ float    sBig[N_EDGES];    // 40 KB: v1/v2 stage OR edge-push accum
    __shared__ float    eS[NW][RE];
    __shared__ unsigned eC[NW][RE];
    __shared__ float    sS_n[RN];
    __shared__ unsigned sC_n[RN];
    __shared__ unsigned scntN[G1];
    __shared__ float    wgt[384];
    __shared__ float    y_loc[RN];

    const int b = blockIdx.x;
    const int t = threadIdx.x;
    const int wv = t >> 6;
    const int lane = t & 63;
    float my_binv = 0.0f;   // valid t < RE
    float my_dinv = 0.0f;   // valid t < RN

    // ---- Phase A': reduce K1's edge partials -> v1 (register accumulation) ----
    if (lane < RE) {
        const int e = b * RE + lane;
        float s = 0.0f; unsigned c = 0u;
        for (int g = wv; g < G1; g += NW) {
            s += P_S1[(size_t)g * N_EDGES + e];
            c += (P_B1[(size_t)g * (N_EDGES / 2) + (e >> 1)] >> ((e & 1) * 16)) & 0xFFFFu;
        }
        eS[wv][lane] = s; eC[wv][lane] = c;
    }
    __syncthreads();
    if (t < RE) {
        float s = 0.0f; unsigned c = 0u;
        #pragma unroll
        for (int k = 0; k < NW; ++k) { s += eS[k][t]; c += eC[k][t]; }
        my_binv = (c > 0u) ? (1.0f / (float)c) : 0.0f;
        st_a(&v1[b * RE + t], s * my_binv);
    }
    bar_arrive(bar, 0);
    // light prep only (keeps every block's arrive->wait gap tiny)
    if (t < RN) { sS_n[t] = 0.0f; sC_n[t] = 0u; }
    if (t < G1) scntN[t] = cntN[(size_t)b * G1 + t];
    if (t < 128) { wgt[t] = W1[t]; wgt[128 + t] = b1[t]; wgt[256 + t] = W2[t]; }
    bar_wait(bar, 0);

    // ---- Phase B: node pass 1 (binN -> registers) + MLP + push to edge partials ----
    const unsigned* baseN = binN + (size_t)b * G1 * SLOT;
    for (int j = t; j < N_EDGES; j += BLK) sBig[j] = v1[j];   // plain cached loads
    __syncthreads();
    unsigned w_reg[ITER];
    #pragma unroll
    for (int it = 0; it < ITER; ++it) {
        const int j = t + it * BLK;
        const int s = j & (SLOT - 1), bb = j >> 6;
        unsigned w = 0xFFFFFFFFu;
        if ((unsigned)s < scntN[bb]) {
            w = baseN[j];
            atomicAdd(&sS_n[w >> 14], sBig[w & 0x3FFFu]);
            atomicAdd(&sC_n[w >> 14], 1u);
        }
        w_reg[it] = w;
    }
    __syncthreads();
    if (t < RN) {
        unsigned c = sC_n[t];
        my_dinv = (c > 0u) ? (1.0f / (float)c) : 0.0f;
        float tt = sS_n[t] * my_dinv;
        float acc = 0.0f;
        #pragma unroll
        for (int f = 0; f < 128; ++f) {
            float h = fmaf(tt, wgt[f], wgt[128 + f]);
            h = fmaxf(h, 0.0f);
            acc = fmaf(h, wgt[256 + f], acc);
        }
        y_loc[t] = acc;
    }
    __syncthreads();
    for (int j = t; j < N_EDGES; j += BLK) sBig[j] = 0.0f;    // becomes push accum
    __syncthreads();
    #pragma unroll
    for (int it = 0; it < ITER; ++it) {
        unsigned w = w_reg[it];
        if (w != 0xFFFFFFFFu) atomicAdd(&sBig[w & 0x3FFFu], y_loc[w >> 14]);
    }
    __syncthreads();
    {
        float* ps = P_S + (size_t)b * N_EDGES;
        for (int j = t; j < N_EDGES; j += BLK) st_a(&ps[j], sBig[j]);
    }
    bar_arrive(bar, 1);
    bar_wait(bar, 1);

    // ---- Phase C: reduce K2 edge partials -> v2 (register accumulation) ----
    if (lane < RE) {
        float acc = 0.0f;
        for (int g = wv; g < GF; g += NW)
            acc += P_S[(size_t)g * N_EDGES + b * RE + lane];  // plain loads
        eS[wv][lane] = acc;
    }
    __syncthreads();
    if (t < RE) {
        float s = 0.0f;
        #pragma unroll
        for (int k = 0; k < NW; ++k) s += eS[k][t];
        st_a(&v2[b * RE + t], s * my_binv);
    }
    bar_arrive(bar, 2);
    if (t < RN) sS_n[t] = 0.0f;   // tiny prep for D
    bar_wait(bar, 2);

    // ---- Phase D: node pass 2 (register replay) + bias -> out ----
    for (int j = t; j < N_EDGES; j += BLK) sBig[j] = v2[j];   // plain cached loads
    __syncthreads();
    #pragma unroll
    for (int it = 0; it < ITER; ++it) {
        unsigned w = w_reg[it];
        if (w != 0xFFFFFFFFu) atomicAdd(&sS_n[w >> 14], sBig[w & 0x3FFFu]);
    }
    __syncthreads();
    if (t < RN) out[b * RN + t] = fmaf(sS_n[t], my_dinv, b2[0]);
}

extern "C" void kernel_launch(void* const* d_in, const int* in_sizes, int n_in,
                              void* d_out, int out_size, void* d_ws, size_t ws_size,
                              hipStream_t stream) {
    const float* x    = (const float*)d_in[0];
    const float* W1   = (const float*)d_in[1];
    const float* b1   = (const float*)d_in[2];
    const float* W2   = (const float*)d_in[3];
    const float* b2   = (const float*)d_in[4];
    const int*   nidx = (const int*)d_in[5];
    const int*   eidx = (const int*)d_in[6];
    float*       out  = (float*)d_out;

    char* ws = (char*)d_ws;
    unsigned* binN = (unsigned*)(ws + 0);
    unsigned* cntN = (unsigned*)(ws + 16384000);
    float*    P_S1 = (float*)(ws + 16640000);
    unsigned* P_B1 = (unsigned*)(ws + 26880000);
    float*    v1   = (float*)(ws + 32000000);
    float*    v2   = (float*)(ws + 32040000);
    float*    P_S  = (float*)(ws + 32080000);
    unsigned* bar  = (unsigned*)(ws + 42080000);

    k_bin_agg<<<G1, BLK, 0, stream>>>(nidx, eidx, x, binN, cntN, P_S1, P_B1, bar);
    k_fused  <<<GF, BLK, 0, stream>>>(binN, cntN, P_S1, P_B1, W1, b1, W2, b2,
                                      v1, v2, P_S, bar, out);
}